// Round 4
// baseline (117.845 us; speedup 1.0000x reference)
//
#include <hip/hip_runtime.h>
#include <hip/hip_bf16.h>
#include <math.h>

// PLANAttention, bf16/MFMA pipeline (round 4: fold fused into bot-fuse GEMM,
// head-major K/Q/V layout for attn locality):
//  1) k_cvt_w: 8 weight mats fp32 -> bf16 (Wb, order: tK,tQ,tV,bK,bQ,bV,tF,bF)
//  2) k_transpose_cvt: feat (B,256,S) fp32 -> featT (B,S,256) bf16   (top+bot)
//  3) k_gemm<0>: fused QKV proj -> K/Q/V head-major bf16 [mat][b*8+h][S][32]
//  4) k_attn: per (pixel,head) wave: S=Q.K^T (1 mfma), O=S.V (2 mfma)
//       q=0 -> tRet bf16 (B,S,256); q=1..9 -> pat bf16 [b][h][9][4096][32]
//  5) k_gemm<1>: fuse-top: C[m=o][n=pix] = Wtf . tRet^T -> fp32 top_out
//  6) k_fuse_bot: fold+fuse: B-tile staged by gathering <=4 pat rows (exact
//       partition, each pat element read once), C = Wbf . fold(pat)^T -> fp32

typedef __attribute__((ext_vector_type(8))) short  bh8;
typedef __attribute__((ext_vector_type(4))) short  bh4;
typedef __attribute__((ext_vector_type(4))) float  f32x4;
typedef unsigned short u16;

static __device__ __forceinline__ u16 f2b(float x) {
    __hip_bfloat16 h = __float2bfloat16(x);
    return __builtin_bit_cast(u16, h);
}
static __device__ __forceinline__ float b2f(u16 u) {
    unsigned v = ((unsigned)u) << 16;
    return __builtin_bit_cast(float, v);
}

// async global->LDS, 16B per lane. Dest must be linear in lane (wave-uniform base + lane*16).
static __device__ __forceinline__ void gload16(const u16* g, u16* l) {
    __builtin_amdgcn_global_load_lds(
        (const __attribute__((address_space(1))) unsigned int*)g,
        (__attribute__((address_space(3))) unsigned int*)l, 16, 0, 0);
}

// ---------------- weight convert: 8 x 256x256 fp32 -> bf16 ----------------
__global__ __launch_bounds__(256) void k_cvt_w(
    const float* w0, const float* w1, const float* w2, const float* w3,
    const float* w4, const float* w5, const float* w6, const float* w7,
    u16* __restrict__ Wb)
{
    const float* srcs[8] = {w0,w1,w2,w3,w4,w5,w6,w7};
    const float* src = srcs[blockIdx.y];
    int i = (blockIdx.x * 256 + threadIdx.x) * 4;
    float4 v = *(const float4*)&src[i];
    u16 tmp[4] = { f2b(v.x), f2b(v.y), f2b(v.z), f2b(v.w) };
    *(uint2*)&Wb[(size_t)blockIdx.y * 65536 + i] = *(uint2*)tmp;
}

// ---------------- transpose + convert: (B,256,S) f32 -> (B,S,256) bf16 ----------------
__global__ __launch_bounds__(256) void k_transpose_cvt(
    const float* __restrict__ in, u16* __restrict__ out, int S)
{
    const int b  = blockIdx.z;
    const int s0 = blockIdx.x * 64, c0 = blockIdx.y * 64;
    in  += (size_t)b * 256 * S;
    out += (size_t)b * S * 256;
    __shared__ float T[64][65];
    const int t = threadIdx.x;
    {
        int cc = t >> 4, f4 = t & 15;
        #pragma unroll
        for (int rep = 0; rep < 4; ++rep) {
            int c = cc + rep * 16;
            float4 v = *(const float4*)&in[(size_t)(c0 + c) * S + s0 + f4 * 4];
            T[c][f4*4+0] = v.x; T[c][f4*4+1] = v.y;
            T[c][f4*4+2] = v.z; T[c][f4*4+3] = v.w;
        }
    }
    __syncthreads();
    {
        int sr = t >> 3, u = t & 7;
        #pragma unroll
        for (int rep = 0; rep < 2; ++rep) {
            int s = sr + rep * 32;
            u16 tmp[8];
            #pragma unroll
            for (int e = 0; e < 8; ++e) tmp[e] = f2b(T[u*8+e][s]);
            *(uint4*)&out[(size_t)(s0 + s) * 256 + c0 + u * 8] = *(uint4*)tmp;
        }
    }
}

// ---------------- bf16 GEMM: C[m][n] = sum_k A[m][k]*B[n][k], K=256 ----------------
// BM=64 (m0=blockIdx.y*64), BN=256 (n0=blockIdx.x*256), BK=64, 4 waves split N.
// Staging: global_load_lds dwordx4, double-buffered, 1 barrier per K-tile,
// 16B-chunk XOR-swizzle on BOTH global source and ds_read (T2 / rule 21).
// MODE 0 (proj): store bf16 head-major: Y[(n>>8)*arrsz + ((b*8+h)<<lgS | pix)*32 + ch]
//                where b=m>>lgS, pix=m&(S-1), h=(n>>5)&7, ch=n&31
// MODE 1 (fuse): store f32 at  Yf[((b*256 + m)<<lgS) + s], b=n>>lgS, s=n&(S-1)
template<int MODE>
__global__ __launch_bounds__(256) void k_gemm(
    const u16* __restrict__ A, const u16* __restrict__ B,
    void* __restrict__ Yv, size_t arrsz, int lgS)
{
    const int n0 = blockIdx.x * 256;
    const int m0 = blockIdx.y * 64;
    const int t  = threadIdx.x;
    const int w  = t >> 6, wl = t & 63, l16 = wl & 15, grp = wl >> 4;

    __shared__ __align__(16) u16 AT[2][64 * 64];
    __shared__ __align__(16) u16 BT[2][256 * 64];

    f32x4 acc[4][4];
    #pragma unroll
    for (int i = 0; i < 4; ++i)
        #pragma unroll
        for (int j = 0; j < 4; ++j) acc[i][j] = (f32x4){0.f, 0.f, 0.f, 0.f};

#define STAGE(bufi, kk) do {                                                  \
        _Pragma("unroll")                                                     \
        for (int it = 0; it < 2; ++it) {                                      \
            int lin = it * 256 + t;                                           \
            int row = lin >> 3, c = lin & 7;                                  \
            int cs = c ^ (row & 7);                                           \
            gload16(&A[(size_t)(m0 + row) * 256 + (kk) + cs * 8],             \
                    &AT[bufi][lin * 8]);                                      \
        }                                                                     \
        _Pragma("unroll")                                                     \
        for (int it = 0; it < 8; ++it) {                                      \
            int lin = it * 256 + t;                                           \
            int row = lin >> 3, c = lin & 7;                                  \
            int cs = c ^ (row & 7);                                           \
            gload16(&B[(size_t)(n0 + row) * 256 + (kk) + cs * 8],             \
                    &BT[bufi][lin * 8]);                                      \
        }                                                                     \
    } while (0)

    STAGE(0, 0);
    int cur = 0;
    for (int kt = 0; kt < 4; ++kt) {
        __syncthreads();   // drains vmcnt(0): buf[cur] staged; prev reads done
        if (kt < 3) STAGE(cur ^ 1, (kt + 1) * 64);   // in flight under compute
        #pragma unroll
        for (int ks = 0; ks < 2; ++ks) {
            bh8 af[4], bf[4];
            #pragma unroll
            for (int mi = 0; mi < 4; ++mi) {
                int row = mi * 16 + l16;
                int pc = (ks * 4 + grp) ^ (row & 7);
                af[mi] = *(const bh8*)&AT[cur][row * 64 + pc * 8];
            }
            #pragma unroll
            for (int ni = 0; ni < 4; ++ni) {
                int row = w * 64 + ni * 16 + l16;
                int pc = (ks * 4 + grp) ^ (row & 7);
                bf[ni] = *(const bh8*)&BT[cur][row * 64 + pc * 8];
            }
            #pragma unroll
            for (int mi = 0; mi < 4; ++mi)
                #pragma unroll
                for (int ni = 0; ni < 4; ++ni)
                    acc[mi][ni] = __builtin_amdgcn_mfma_f32_16x16x32_bf16(
                        af[mi], bf[ni], acc[mi][ni], 0, 0, 0);
        }
        cur ^= 1;
    }
#undef STAGE

    // epilogue: C[m][n], m = m0+mi*16+grp*4+r, n = n0+w*64+ni*16+l16
    #pragma unroll
    for (int mi = 0; mi < 4; ++mi)
        #pragma unroll
        for (int ni = 0; ni < 4; ++ni)
            #pragma unroll
            for (int r = 0; r < 4; ++r) {
                int m = m0 + mi*16 + grp*4 + r;
                int n = n0 + w*64 + ni*16 + l16;
                float val = acc[mi][ni][r];
                if (MODE == 0) {
                    u16* Yp = (u16*)Yv;
                    int mat = n >> 8;            // 0=K,1=Q,2=V
                    int h   = (n >> 5) & 7;
                    int ch  = n & 31;
                    int bb  = m >> lgS, pix = m & ((1 << lgS) - 1);
                    Yp[(size_t)mat * arrsz +
                       ((((size_t)bb * 8 + h) << lgS) + pix) * 32 + ch] = f2b(val);
                } else {
                    float* Yf = (float*)Yv;
                    int bb = n >> lgS, s = n & ((1 << lgS) - 1);
                    Yf[(((size_t)bb * 256 + m) << lgS) + s] = val;
                }
            }
}

// ---------------- attention: one wave per (pixel, head) ----------------
// K/Q/V head-major: [b*8+h][S][32]
__global__ __launch_bounds__(256) void k_attn(
    const u16* __restrict__ tK, const u16* __restrict__ tQ, const u16* __restrict__ tV,
    const u16* __restrict__ bK, const u16* __restrict__ bQ, const u16* __restrict__ bV,
    u16* __restrict__ tRet, u16* __restrict__ pat)
{
    const int pix = blockIdx.x;     // 0..4095
    const int b   = blockIdx.y;
    const int w   = threadIdx.x >> 6;
    const int wl  = threadIdx.x & 63;
    const int l16 = wl & 15, grp = wl >> 4;
    const int y = pix >> 6, x = pix & 63;

    __shared__ u16 Ssm[4][16][24];        // [wave][q][kpos], stride 48B
    __shared__ __align__(16) u16 Vsm[4][2][16][16]; // [wave][v-half][kpos][v16]

    // position p = l16: p=0 top pixel, p=1..9 bot neighbor, p>=10 pad
    const int p = l16;
    bool pvalid = false; int bpix = 0; const bool istop = (p == 0);
    if (p == 0) pvalid = true;
    else if (p < 10) {
        int pm = p - 1; int i = (pm * 11) >> 5; int j = pm - 3 * i;
        int by = 2 * y + i - 1, bx = 2 * x + j - 1;
        pvalid = ((unsigned)by < 128u) && ((unsigned)bx < 128u);
        bpix = by * 128 + bx;
    }
    const float scale = 0.17677669529663687f; // 1/sqrt(32)

    #pragma unroll
    for (int hi = 0; hi < 2; ++hi) {
        const int h = w + hi * 4;
        const size_t off = istop
            ? ((((size_t)b * 8 + h) * 4096  + pix)  * 32 + grp * 8)
            : ((((size_t)b * 8 + h) * 16384 + bpix) * 32 + grp * 8);
        bh8 aQ = {}, aK = {}, vV = {};
        if (pvalid) {
            if (istop) {
                aQ = *(const bh8*)(tQ + off);
                aK = *(const bh8*)(tK + off);
                vV = *(const bh8*)(tV + off);
            } else {
                aQ = *(const bh8*)(bQ + off);
                aK = *(const bh8*)(bK + off);
                vV = *(const bh8*)(bV + off);
            }
        }
        // stage V rows (zeros for invalid rows): half = grp>>1, chunk (grp&1)*8
        *(bh8*)&Vsm[w][grp >> 1][p][(grp & 1) * 8] = vV;

        // S = Q.K^T   (A rows = query pos, B cols = key pos, k = d contiguous)
        f32x4 z = {0.f, 0.f, 0.f, 0.f};
        f32x4 sC = __builtin_amdgcn_mfma_f32_16x16x32_bf16(aQ, aK, z, 0, 0, 0);
        #pragma unroll
        for (int r = 0; r < 4; ++r)
            Ssm[w][grp * 4 + r][l16] = f2b(sC[r] * scale);

        // A_S: row q=l16, k-slots (grp,i<4) = kpos 4*grp+i ; slots i>=4 zero
        bh8 aS = {};
        *(bh4*)&aS = *(const bh4*)&Ssm[w][l16][grp * 4];

        // B_V: slot (grp,i<4) = V[kpos=4*grp+i][v], consistent with A_S labeling
        bh8 bv0 = {}, bv1 = {};
        #pragma unroll
        for (int j = 0; j < 4; ++j) {
            bv0[j] = (short)Vsm[w][0][grp * 4 + j][l16];
            bv1[j] = (short)Vsm[w][1][grp * 4 + j][l16];
        }
        f32x4 oc0 = __builtin_amdgcn_mfma_f32_16x16x32_bf16(aS, bv0, z, 0, 0, 0);
        f32x4 oc1 = __builtin_amdgcn_mfma_f32_16x16x32_bf16(aS, bv1, z, 0, 0, 0);

        // outputs: row q = grp*4+r, col v = l16 (+16 for oc1)
        if (grp == 0) {
            size_t o = ((size_t)b * 4096 + pix) * 256 + (size_t)h * 32;
            tRet[o + l16]      = f2b(oc0[0]);
            tRet[o + 16 + l16] = f2b(oc1[0]);
        }
        #pragma unroll
        for (int r = 0; r < 4; ++r) {
            int q = grp * 4 + r;
            if (q >= 1 && q <= 9) {
                size_t base = ((((size_t)b * 8 + h) * 9 + (q - 1)) * 4096 + pix) * 32;
                pat[base + l16]      = f2b(oc0[r]);
                pat[base + 16 + l16] = f2b(oc1[r]);
            }
        }
    }
}

// ---------------- fused fold + bot-fuse GEMM ----------------
// C[m=o(256)][n=bpix] = sum_v Wf[o][v] * (sum_{valid (q,tpix)} pat[b][h][q][tpix][vv])
// BM=256 (all o in one block -> gather done once per n-tile), BN=64 pixels, BK=64.
// A (Wf) staged via gload_lds; B staged by gather+sum+pack+swizzled ds_write.
__global__ __launch_bounds__(256) void k_fuse_bot(
    const u16* __restrict__ Wf, const u16* __restrict__ pat,
    float* __restrict__ bot_out)
{
    const int t   = threadIdx.x;
    const int w   = t >> 6, wl = t & 63, l16 = wl & 15, grp = wl >> 4;
    const int n0g = blockIdx.x * 64;        // global pixel-col base (b-major)
    const int b   = n0g >> 14;
    const int sp0 = n0g & 16383;
    const int by  = sp0 >> 7;               // uniform for the whole tile
    const int bx0 = sp0 & 127;              // 0 or 64

    __shared__ __align__(16) u16 AT[2][256 * 64];   // 64 KB
    __shared__ __align__(16) u16 BT[2][64 * 64];    // 16 KB

    // y-candidates (block-uniform): i s.t. (by+1-i) even, y=(by+1-i)/2 in [0,64)
    int nvy = 0; int ys[2], is_[2];
    #pragma unroll
    for (int iy = 0; iy < 3; ++iy) {
        int num = by + 1 - iy;
        if (!(num & 1)) {
            int yy = num >> 1;
            if ((unsigned)yy < 64u) { ys[nvy] = yy; is_[nvy] = iy; ++nvy; }
        }
    }

    f32x4 acc[4][4];
    #pragma unroll
    for (int i = 0; i < 4; ++i)
        #pragma unroll
        for (int j = 0; j < 4; ++j) acc[i][j] = (f32x4){0.f, 0.f, 0.f, 0.f};

#define STAGE_A(bufi, kk) do {                                                \
        _Pragma("unroll")                                                     \
        for (int it = 0; it < 8; ++it) {                                      \
            int lin = it * 256 + t;                                           \
            int row = lin >> 3, c = lin & 7;                                  \
            int cs = c ^ (row & 7);                                           \
            gload16(&Wf[(size_t)row * 256 + (kk) + cs * 8],                   \
                    &AT[bufi][lin * 8]);                                      \
        }                                                                     \
    } while (0)

#define STAGE_B(bufi, kk) do {                                                \
        _Pragma("unroll")                                                     \
        for (int it = 0; it < 2; ++it) {                                      \
            int task = it * 256 + t;                                          \
            int row = task >> 3, c8 = task & 7;                               \
            int cb = (kk) + c8 * 8;                                           \
            int h = cb >> 5, vv0 = cb & 31;                                   \
            int bx = bx0 + row;                                               \
            float fa[8];                                                      \
            _Pragma("unroll")                                                 \
            for (int e = 0; e < 8; ++e) fa[e] = 0.f;                          \
            _Pragma("unroll")                                                 \
            for (int yi = 0; yi < 2; ++yi) {                                  \
                if (yi < nvy) {                                               \
                    int yy = ys[yi], ii = is_[yi];                            \
                    _Pragma("unroll")                                         \
                    for (int j = 0; j < 3; ++j) {                             \
                        int num = bx + 1 - j;                                 \
                        if (!(num & 1)) {                                     \
                            int xx = num >> 1;                                \
                            if ((unsigned)xx < 64u) {                         \
                                int q = ii * 3 + j;                           \
                                size_t addr = ((((size_t)b * 8 + h) * 9 + q)  \
                                               * 4096 + (yy * 64 + xx)) * 32  \
                                              + vv0;                          \
                                uint4 pv = *(const uint4*)&pat[addr];         \
                                const u16* pp = (const u16*)&pv;              \
                                _Pragma("unroll")                             \
                                for (int e = 0; e < 8; ++e)                   \
                                    fa[e] += b2f(pp[e]);                      \
                            }                                                 \
                        }                                                     \
                    }                                                         \
                }                                                             \
            }                                                                 \
            u16 tmp[8];                                                       \
            _Pragma("unroll")                                                 \
            for (int e = 0; e < 8; ++e) tmp[e] = f2b(fa[e]);                  \
            int cs = c8 ^ (row & 7);                                          \
            *(uint4*)&BT[bufi][row * 64 + cs * 8] = *(uint4*)tmp;             \
        }                                                                     \
    } while (0)

    STAGE_A(0, 0);
    STAGE_B(0, 0);
    int cur = 0;
    for (int kt = 0; kt < 4; ++kt) {
        __syncthreads();
        if (kt < 3) { STAGE_A(cur ^ 1, (kt + 1) * 64); STAGE_B(cur ^ 1, (kt + 1) * 64); }
        #pragma unroll
        for (int ks = 0; ks < 2; ++ks) {
            bh8 af[4], bf[4];
            #pragma unroll
            for (int mi = 0; mi < 4; ++mi) {
                int row = w * 64 + mi * 16 + l16;
                int pc = (ks * 4 + grp) ^ (row & 7);
                af[mi] = *(const bh8*)&AT[cur][row * 64 + pc * 8];
            }
            #pragma unroll
            for (int ni = 0; ni < 4; ++ni) {
                int row = ni * 16 + l16;
                int pc = (ks * 4 + grp) ^ (row & 7);
                bf[ni] = *(const bh8*)&BT[cur][row * 64 + pc * 8];
            }
            #pragma unroll
            for (int mi = 0; mi < 4; ++mi)
                #pragma unroll
                for (int ni = 0; ni < 4; ++ni)
                    acc[mi][ni] = __builtin_amdgcn_mfma_f32_16x16x32_bf16(
                        af[mi], bf[ni], acc[mi][ni], 0, 0, 0);
        }
        cur ^= 1;
    }
#undef STAGE_A
#undef STAGE_B

    // epilogue: m = w*64+mi*16+grp*4+r (o), n = n0g+ni*16+l16 (pixel)
    #pragma unroll
    for (int mi = 0; mi < 4; ++mi)
        #pragma unroll
        for (int ni = 0; ni < 4; ++ni)
            #pragma unroll
            for (int r = 0; r < 4; ++r) {
                int m = w * 64 + mi * 16 + grp * 4 + r;
                int s = sp0 + ni * 16 + l16;
                bot_out[((size_t)b * 256 + m) * 16384 + s] = acc[mi][ni][r];
            }
}

extern "C" void kernel_launch(void* const* d_in, const int* in_sizes, int n_in,
                              void* d_out, int out_size, void* d_ws, size_t ws_size,
                              hipStream_t stream) {
    const float* top_feat = (const float*)d_in[0];
    const float* bot_feat = (const float*)d_in[1];

    float* out     = (float*)d_out;
    float* top_out = out;                            // (2,256,64,64)
    float* bot_out = out + (size_t)2 * 256 * 4096;   // (2,256,128,128)

    const size_t TOPU = (size_t)2 * 4096  * 256;   // ushort counts
    const size_t BOTU = (size_t)2 * 16384 * 256;
    char* p = (char*)d_ws;
    u16* Wb     = (u16*)p;  p += (size_t)8 * 65536 * 2;   // 1.0 MB
    u16* topT   = (u16*)p;  p += TOPU * 2;                // 4.2 MB
    u16* botT   = (u16*)p;  p += BOTU * 2;                // 16.8 MB
    u16* tK     = (u16*)p;  p += TOPU * 2;
    u16* tQ     = (u16*)p;  p += TOPU * 2;
    u16* tV     = (u16*)p;  p += TOPU * 2;                // 12.6 MB
    u16* bK     = (u16*)p;  p += BOTU * 2;
    u16* bQ     = (u16*)p;  p += BOTU * 2;
    u16* bV     = (u16*)p;  p += BOTU * 2;                // 50.3 MB
    u16* tRet   = (u16*)p;  p += TOPU * 2;                // 4.2 MB
    u16* pat    = (u16*)p;  p += (size_t)2*8*9*4096*32*2; // 37.7 MB

    dim3 blk(256);

    // weights -> bf16 (order: tK,tQ,tV,bK,bQ,bV,tFuse,bFuse)
    k_cvt_w<<<dim3(64, 8), blk, 0, stream>>>(
        (const float*)d_in[2], (const float*)d_in[3], (const float*)d_in[4],
        (const float*)d_in[5], (const float*)d_in[6], (const float*)d_in[7],
        (const float*)d_in[8], (const float*)d_in[9], Wb);

    // feat transpose+convert
    k_transpose_cvt<<<dim3(64, 4, 2),  blk, 0, stream>>>(top_feat, topT, 4096);
    k_transpose_cvt<<<dim3(256, 4, 2), blk, 0, stream>>>(bot_feat, botT, 16384);

    // fused QKV projections (N = 768 = [K|Q|V]) -> head-major
    k_gemm<0><<<dim3(3, 128), blk, 0, stream>>>(topT, Wb,           (void*)tK, TOPU, 12);
    k_gemm<0><<<dim3(3, 512), blk, 0, stream>>>(botT, Wb + 3*65536, (void*)bK, BOTU, 14);

    // attention
    k_attn<<<dim3(4096, 2), blk, 0, stream>>>(tK, tQ, tV, bK, bQ, bV, tRet, pat);

    // fuse-top GEMM -> fp32 channel-major
    k_gemm<1><<<dim3(32, 4), blk, 0, stream>>>(Wb + 6*65536, tRet, (void*)top_out, 0, 12);

    // fused fold + fuse-bot GEMM -> fp32 channel-major
    k_fuse_bot<<<dim3(512), blk, 0, stream>>>(Wb + 7*65536, pat, bot_out);
}

// Round 5
// 102.466 us; speedup vs baseline: 1.1501x; 1.1501x over previous
//
#include <hip/hip_runtime.h>
#include <hip/hip_bf16.h>
#include <math.h>

// PLANAttention, bf16/MFMA pipeline (round 5: round-3 math, 9 -> 5 dispatches):
//  1) k_prep: weights fp32->bf16 (Wb) + feat transpose (B,256,S)f32 -> (B,S,256)bf16
//  2) k_proj: fused QKV proj (top+bot merged): C[m=pixrow][n=o(768)] -> pixel-major bf16
//  3) k_attn: per (pixel,head) wave: S=Q.K^T (1 mfma), O=S.V (2 mfma)
//       q=0 -> tRet bf16 (B,S,256); q=1..9 -> pat bf16 [b][h][9][4096][32]
//  4) k_fold: pat -> botRet bf16 (B,Sb,256) (gather <=4 windows, no atomics)
//  5) k_fuse: fuse-top + fuse-bot merged: C[m=o][n=pixrow] = Wf . ret^T -> fp32 d_out

typedef __attribute__((ext_vector_type(8))) short  bh8;
typedef __attribute__((ext_vector_type(4))) short  bh4;
typedef __attribute__((ext_vector_type(4))) float  f32x4;
typedef unsigned short u16;

static __device__ __forceinline__ u16 f2b(float x) {
    __hip_bfloat16 h = __float2bfloat16(x);
    return __builtin_bit_cast(u16, h);
}
static __device__ __forceinline__ float b2f(u16 u) {
    unsigned v = ((unsigned)u) << 16;
    return __builtin_bit_cast(float, v);
}

// async global->LDS, 16B per lane. Dest must be linear in lane (wave-uniform base + lane*16).
static __device__ __forceinline__ void gload16(const u16* g, u16* l) {
    __builtin_amdgcn_global_load_lds(
        (const __attribute__((address_space(1))) unsigned int*)g,
        (__attribute__((address_space(3))) unsigned int*)l, 16, 0, 0);
}

// ---------------- prep: weight cvt (blocks 0..511) + transposes (512..3071) ----------------
__global__ __launch_bounds__(256) void k_prep(
    const float* w0, const float* w1, const float* w2, const float* w3,
    const float* w4, const float* w5, const float* w6, const float* w7,
    const float* __restrict__ top_feat, const float* __restrict__ bot_feat,
    u16* __restrict__ Wb, u16* __restrict__ topT, u16* __restrict__ botT)
{
    __shared__ float T[64][65];
    const int bid = blockIdx.x;
    const int t   = threadIdx.x;

    if (bid < 512) {
        // ---- weight convert: mat = bid>>6, chunk = bid&63 ----
        const int mat = bid >> 6;
        const float* src;
        switch (mat) {
            case 0: src = w0; break; case 1: src = w1; break;
            case 2: src = w2; break; case 3: src = w3; break;
            case 4: src = w4; break; case 5: src = w5; break;
            case 6: src = w6; break; default: src = w7; break;
        }
        int i = ((bid & 63) * 256 + t) * 4;
        float4 v = *(const float4*)&src[i];
        u16 tmp[4] = { f2b(v.x), f2b(v.y), f2b(v.z), f2b(v.w) };
        *(uint2*)&Wb[(size_t)mat * 65536 + i] = *(uint2*)tmp;
        return;
    }

    // ---- transpose + convert ----
    const float* in; u16* outp; int S, b, s0, c0;
    if (bid < 1024) {
        int i = bid - 512;           // top: 2 b x 4 c-tiles x 64 s-tiles
        b = i >> 8; int rem = i & 255;
        s0 = (rem & 63) * 64; c0 = (rem >> 6) * 64;
        in = top_feat; outp = topT; S = 4096;
    } else {
        int i = bid - 1024;          // bot: 2 b x 4 c-tiles x 256 s-tiles
        b = i >> 10; int rem = i & 1023;
        s0 = (rem & 255) * 64; c0 = (rem >> 8) * 64;
        in = bot_feat; outp = botT; S = 16384;
    }
    in   += (size_t)b * 256 * S;
    outp += (size_t)b * S * 256;
    {
        int cc = t >> 4, f4 = t & 15;
        #pragma unroll
        for (int rep = 0; rep < 4; ++rep) {
            int c = cc + rep * 16;
            float4 v = *(const float4*)&in[(size_t)(c0 + c) * S + s0 + f4 * 4];
            T[c][f4*4+0] = v.x; T[c][f4*4+1] = v.y;
            T[c][f4*4+2] = v.z; T[c][f4*4+3] = v.w;
        }
    }
    __syncthreads();
    {
        int sr = t >> 3, u = t & 7;
        #pragma unroll
        for (int rep = 0; rep < 2; ++rep) {
            int s = sr + rep * 32;
            u16 tmp[8];
            #pragma unroll
            for (int e = 0; e < 8; ++e) tmp[e] = f2b(T[u*8+e][s]);
            *(uint4*)&outp[(size_t)(s0 + s) * 256 + c0 + u * 8] = *(uint4*)tmp;
        }
    }
}

// Shared GEMM staging/compute (round-3 verified): C[m][n] = sum_k A[m][k]*B[n][k], K=256.
// BM=64, BN=256, BK=64, 4 waves split N. global_load_lds dwordx4, double-buffered,
// 1 barrier per K-tile, 16B-chunk XOR-swizzle on BOTH global source and ds_read.
#define GEMM_STAGE(bufi, kk) do {                                             \
        _Pragma("unroll")                                                     \
        for (int it = 0; it < 2; ++it) {                                      \
            int lin = it * 256 + t;                                           \
            int row = lin >> 3, c = lin & 7;                                  \
            int cs = c ^ (row & 7);                                           \
            gload16(&A[(size_t)(m0 + row) * 256 + (kk) + cs * 8],             \
                    &AT[bufi][lin * 8]);                                      \
        }                                                                     \
        _Pragma("unroll")                                                     \
        for (int it = 0; it < 8; ++it) {                                      \
            int lin = it * 256 + t;                                           \
            int row = lin >> 3, c = lin & 7;                                  \
            int cs = c ^ (row & 7);                                           \
            gload16(&B[(size_t)(n0 + row) * 256 + (kk) + cs * 8],             \
                    &BT[bufi][lin * 8]);                                      \
        }                                                                     \
    } while (0)

#define GEMM_MAIN()                                                           \
    GEMM_STAGE(0, 0);                                                         \
    int cur = 0;                                                              \
    for (int kt = 0; kt < 4; ++kt) {                                          \
        __syncthreads();                                                      \
        if (kt < 3) GEMM_STAGE(cur ^ 1, (kt + 1) * 64);                       \
        _Pragma("unroll")                                                     \
        for (int ks = 0; ks < 2; ++ks) {                                      \
            bh8 af[4], bf[4];                                                 \
            _Pragma("unroll")                                                 \
            for (int mi = 0; mi < 4; ++mi) {                                  \
                int row = mi * 16 + l16;                                      \
                int pc = (ks * 4 + grp) ^ (row & 7);                          \
                af[mi] = *(const bh8*)&AT[cur][row * 64 + pc * 8];            \
            }                                                                 \
            _Pragma("unroll")                                                 \
            for (int ni = 0; ni < 4; ++ni) {                                  \
                int row = w * 64 + ni * 16 + l16;                             \
                int pc = (ks * 4 + grp) ^ (row & 7);                          \
                bf[ni] = *(const bh8*)&BT[cur][row * 64 + pc * 8];            \
            }                                                                 \
            _Pragma("unroll")                                                 \
            for (int mi = 0; mi < 4; ++mi)                                    \
                _Pragma("unroll")                                             \
                for (int ni = 0; ni < 4; ++ni)                                \
                    acc[mi][ni] = __builtin_amdgcn_mfma_f32_16x16x32_bf16(    \
                        af[mi], bf[ni], acc[mi][ni], 0, 0, 0);                \
        }                                                                     \
        cur ^= 1;                                                             \
    }

// ---------------- proj (top + bot merged): bf16 pixel-major K/Q/V ----------------
// grid (3, 640): y<128 top (m0=y*64), else bot (m0=(y-128)*64). N=768=[K|Q|V].
// store: Yp[(n>>8)*arrsz + m*256 + (n&255)]
__global__ __launch_bounds__(256) void k_proj(
    const u16* __restrict__ topT, const u16* __restrict__ botT,
    const u16* __restrict__ Wb,
    u16* __restrict__ tK, u16* __restrict__ bK, size_t TOPU, size_t BOTU)
{
    const int yb    = blockIdx.y;
    const bool istop = yb < 128;
    const u16* A = istop ? topT : botT;
    const u16* B = istop ? Wb : (Wb + 3 * 65536);
    u16* Yp      = istop ? tK : bK;
    const size_t arrsz = istop ? TOPU : BOTU;
    const int m0 = (istop ? yb : (yb - 128)) * 64;
    const int n0 = blockIdx.x * 256;
    const int t  = threadIdx.x;
    const int w  = t >> 6, wl = t & 63, l16 = wl & 15, grp = wl >> 4;

    __shared__ __align__(16) u16 AT[2][64 * 64];
    __shared__ __align__(16) u16 BT[2][256 * 64];

    f32x4 acc[4][4];
    #pragma unroll
    for (int i = 0; i < 4; ++i)
        #pragma unroll
        for (int j = 0; j < 4; ++j) acc[i][j] = (f32x4){0.f, 0.f, 0.f, 0.f};

    GEMM_MAIN();

    #pragma unroll
    for (int mi = 0; mi < 4; ++mi)
        #pragma unroll
        for (int ni = 0; ni < 4; ++ni)
            #pragma unroll
            for (int r = 0; r < 4; ++r) {
                int m = m0 + mi*16 + grp*4 + r;
                int n = n0 + w*64 + ni*16 + l16;
                Yp[(size_t)(n >> 8) * arrsz + (size_t)m * 256 + (n & 255)]
                    = f2b(acc[mi][ni][r]);
            }
}

// ---------------- fuse (top + bot merged): C[m=o][n=pixrow] -> fp32 ----------------
// blocks [0,128): top (lgS=12, n-tiles 32, m-tiles 4); [128,640): bot (lgS=14, 128x4)
__global__ __launch_bounds__(256) void k_fuse(
    const u16* __restrict__ Wb, const u16* __restrict__ tRet,
    const u16* __restrict__ botRet, float* __restrict__ top_out,
    float* __restrict__ bot_out)
{
    const int bid = blockIdx.x;
    const u16* A; const u16* B; float* Yf; int lgS, n0, m0;
    if (bid < 128) {
        A = Wb + 6 * 65536; B = tRet; Yf = top_out; lgS = 12;
        n0 = (bid & 31) * 256; m0 = (bid >> 5) * 64;
    } else {
        int i = bid - 128;
        A = Wb + 7 * 65536; B = botRet; Yf = bot_out; lgS = 14;
        n0 = (i & 127) * 256; m0 = (i >> 7) * 64;
    }
    const int t  = threadIdx.x;
    const int w  = t >> 6, wl = t & 63, l16 = wl & 15, grp = wl >> 4;

    __shared__ __align__(16) u16 AT[2][64 * 64];
    __shared__ __align__(16) u16 BT[2][256 * 64];

    f32x4 acc[4][4];
    #pragma unroll
    for (int i = 0; i < 4; ++i)
        #pragma unroll
        for (int j = 0; j < 4; ++j) acc[i][j] = (f32x4){0.f, 0.f, 0.f, 0.f};

    GEMM_MAIN();

    #pragma unroll
    for (int mi = 0; mi < 4; ++mi)
        #pragma unroll
        for (int ni = 0; ni < 4; ++ni)
            #pragma unroll
            for (int r = 0; r < 4; ++r) {
                int m = m0 + mi*16 + grp*4 + r;
                int n = n0 + w*64 + ni*16 + l16;
                int bb = n >> lgS, s = n & ((1 << lgS) - 1);
                Yf[(((size_t)bb * 256 + m) << lgS) + s] = acc[mi][ni][r];
            }
}

// ---------------- attention: one wave per (pixel, head-pair) ----------------
__global__ __launch_bounds__(256) void k_attn(
    const u16* __restrict__ tK, const u16* __restrict__ tQ, const u16* __restrict__ tV,
    const u16* __restrict__ bK, const u16* __restrict__ bQ, const u16* __restrict__ bV,
    u16* __restrict__ tRet, u16* __restrict__ pat)
{
    const int pix = blockIdx.x;     // 0..4095
    const int b   = blockIdx.y;
    const int w   = threadIdx.x >> 6;
    const int wl  = threadIdx.x & 63;
    const int l16 = wl & 15, grp = wl >> 4;
    const int y = pix >> 6, x = pix & 63;

    __shared__ u16 Ssm[4][16][24];        // [wave][q][kpos], stride 48B
    __shared__ __align__(16) u16 Vsm[4][2][16][16]; // [wave][v-half][kpos][v16]

    // position p = l16: p=0 top pixel, p=1..9 bot neighbor, p>=10 pad
    const int p = l16;
    bool pvalid = false; int bpix = 0; const bool istop = (p == 0);
    if (p == 0) pvalid = true;
    else if (p < 10) {
        int pm = p - 1; int i = (pm * 11) >> 5; int j = pm - 3 * i;
        int by = 2 * y + i - 1, bx = 2 * x + j - 1;
        pvalid = ((unsigned)by < 128u) && ((unsigned)bx < 128u);
        bpix = by * 128 + bx;
    }
    const size_t topRow = ((size_t)b * 4096  + pix)  * 256;
    const size_t botRow = ((size_t)b * 16384 + bpix) * 256;
    const float scale = 0.17677669529663687f; // 1/sqrt(32)

    #pragma unroll
    for (int hi = 0; hi < 2; ++hi) {
        const int h = w + hi * 4;
        const size_t off = (istop ? topRow : botRow) + h * 32 + grp * 8;
        bh8 aQ = {}, aK = {}, vV = {};
        if (pvalid) {
            if (istop) {
                aQ = *(const bh8*)(tQ + off);
                aK = *(const bh8*)(tK + off);
                vV = *(const bh8*)(tV + off);
            } else {
                aQ = *(const bh8*)(bQ + off);
                aK = *(const bh8*)(bK + off);
                vV = *(const bh8*)(bV + off);
            }
        }
        // stage V rows (zeros for invalid rows): half = grp>>1, chunk (grp&1)*8
        *(bh8*)&Vsm[w][grp >> 1][p][(grp & 1) * 8] = vV;

        // S = Q.K^T   (A rows = query pos, B cols = key pos, k = d contiguous)
        f32x4 z = {0.f, 0.f, 0.f, 0.f};
        f32x4 sC = __builtin_amdgcn_mfma_f32_16x16x32_bf16(aQ, aK, z, 0, 0, 0);
        #pragma unroll
        for (int r = 0; r < 4; ++r)
            Ssm[w][grp * 4 + r][l16] = f2b(sC[r] * scale);

        // A_S: row q=l16, k-slots (grp,i<4) = kpos 4*grp+i ; slots i>=4 zero
        bh8 aS = {};
        *(bh4*)&aS = *(const bh4*)&Ssm[w][l16][grp * 4];

        // B_V: slot (grp,i<4) = V[kpos=4*grp+i][v], consistent with A_S labeling
        bh8 bv0 = {}, bv1 = {};
        #pragma unroll
        for (int j = 0; j < 4; ++j) {
            bv0[j] = (short)Vsm[w][0][grp * 4 + j][l16];
            bv1[j] = (short)Vsm[w][1][grp * 4 + j][l16];
        }
        f32x4 oc0 = __builtin_amdgcn_mfma_f32_16x16x32_bf16(aS, bv0, z, 0, 0, 0);
        f32x4 oc1 = __builtin_amdgcn_mfma_f32_16x16x32_bf16(aS, bv1, z, 0, 0, 0);

        // outputs: row q = grp*4+r, col v = l16 (+16 for oc1)
        if (grp == 0) {
            size_t o = topRow + (size_t)h * 32;
            tRet[o + l16]      = f2b(oc0[0]);
            tRet[o + 16 + l16] = f2b(oc1[0]);
        }
        #pragma unroll
        for (int r = 0; r < 4; ++r) {
            int q = grp * 4 + r;
            if (q >= 1 && q <= 9) {
                size_t base = ((((size_t)b * 8 + h) * 9 + (q - 1)) * 4096 + pix) * 32;
                pat[base + l16]      = f2b(oc0[r]);
                pat[base + 16 + l16] = f2b(oc1[r]);
            }
        }
    }
}

// ---------------- fold: pat [b][h][9][4096][32] -> botRet (B,16384,256) bf16 ----------------
__global__ __launch_bounds__(256) void k_fold(
    const u16* __restrict__ pat, u16* __restrict__ botRet)
{
    int tid = blockIdx.x * 256 + threadIdx.x;       // 1,048,576 threads
    int vchunk = tid & 3;                           // 8 v's each
    int ri = tid >> 2;                              // (b*16384 + bpix)*8 + h
    int b = ri >> 17;
    int bpix = (ri >> 3) & 16383;
    int h = ri & 7;
    int by = bpix >> 7, bx = bpix & 127;
    int v0 = vchunk * 8;

    float acc[8];
    #pragma unroll
    for (int e = 0; e < 8; ++e) acc[e] = 0.f;

    for (int iy = 0; iy < 3; ++iy) {
        int ty = by + 1 - iy;
        if (ty & 1) continue;
        int yy = ty >> 1;
        if ((unsigned)yy >= 64u) continue;
        for (int jx = 0; jx < 3; ++jx) {
            int tx = bx + 1 - jx;
            if (tx & 1) continue;
            int xx = tx >> 1;
            if ((unsigned)xx >= 64u) continue;
            int q = iy * 3 + jx;
            size_t addr = ((((size_t)b * 8 + h) * 9 + q) * 4096 + (yy * 64 + xx)) * 32 + v0;
            uint4 pv = *(const uint4*)&pat[addr];
            const u16* pp = (const u16*)&pv;
            #pragma unroll
            for (int e = 0; e < 8; ++e) acc[e] += b2f(pp[e]);
        }
    }
    u16 tmp[8];
    #pragma unroll
    for (int e = 0; e < 8; ++e) tmp[e] = f2b(acc[e]);
    *(uint4*)&botRet[((size_t)b * 16384 + bpix) * 256 + h * 32 + v0] = *(uint4*)tmp;
}

extern "C" void kernel_launch(void* const* d_in, const int* in_sizes, int n_in,
                              void* d_out, int out_size, void* d_ws, size_t ws_size,
                              hipStream_t stream) {
    const float* top_feat = (const float*)d_in[0];
    const float* bot_feat = (const float*)d_in[1];

    float* out     = (float*)d_out;
    float* top_out = out;                            // (2,256,64,64)
    float* bot_out = out + (size_t)2 * 256 * 4096;   // (2,256,128,128)

    const size_t TOPU = (size_t)2 * 4096  * 256;   // ushort counts
    const size_t BOTU = (size_t)2 * 16384 * 256;
    char* p = (char*)d_ws;
    u16* Wb     = (u16*)p;  p += (size_t)8 * 65536 * 2;   // 1.0 MB
    u16* topT   = (u16*)p;  p += TOPU * 2;                // 4.2 MB
    u16* botT   = (u16*)p;  p += BOTU * 2;                // 16.8 MB
    u16* tK     = (u16*)p;  p += TOPU * 2;
    u16* tQ     = (u16*)p;  p += TOPU * 2;
    u16* tV     = (u16*)p;  p += TOPU * 2;                // 12.6 MB
    u16* bK     = (u16*)p;  p += BOTU * 2;
    u16* bQ     = (u16*)p;  p += BOTU * 2;
    u16* bV     = (u16*)p;  p += BOTU * 2;                // 50.3 MB
    u16* tRet   = (u16*)p;  p += TOPU * 2;                // 4.2 MB
    u16* pat    = (u16*)p;  p += (size_t)2*8*9*4096*32*2; // 37.7 MB
    u16* botRet = (u16*)p;  p += BOTU * 2;                // 16.8 MB

    dim3 blk(256);

    // prep: weights cvt + feat transposes (1 dispatch)
    k_prep<<<dim3(3072), blk, 0, stream>>>(
        (const float*)d_in[2], (const float*)d_in[3], (const float*)d_in[4],
        (const float*)d_in[5], (const float*)d_in[6], (const float*)d_in[7],
        (const float*)d_in[8], (const float*)d_in[9],
        top_feat, bot_feat, Wb, topT, botT);

    // fused QKV projections, top+bot merged (1 dispatch)
    k_proj<<<dim3(3, 640), blk, 0, stream>>>(topT, botT, Wb, tK, bK, TOPU, BOTU);

    // attention
    k_attn<<<dim3(4096, 2), blk, 0, stream>>>(tK, tQ, tV, bK, bQ, bV, tRet, pat);

    // fold bot windows
    k_fold<<<dim3(4096), blk, 0, stream>>>(pat, botRet);

    // fuse GEMMs, top+bot merged (1 dispatch) -> fp32 channel-major outputs
    k_fuse<<<dim3(640), blk, 0, stream>>>(Wb, tRet, botRet, top_out, bot_out);
}

// Round 6
// 102.319 us; speedup vs baseline: 1.1517x; 1.0014x over previous
//
#include <hip/hip_runtime.h>
#include <hip/hip_bf16.h>
#include <math.h>

// PLANAttention, bf16/MFMA pipeline (round 6: transpose fused into proj A-staging):
//  1) k_cvt_w: 8 weight mats fp32 -> bf16 (Wb)   [tiny]
//  2) k_proj: fused QKV proj (top+bot merged): A = feat (channel-major fp32,
//       reg-staged transpose+cvt into swizzled LDS), B = Wqkv bf16 (gload16).
//       C[m=pixrow][n=o(768)] -> pixel-major bf16 K/Q/V.
//  3) k_attn: per (pixel,head) wave: S=Q.K^T (1 mfma), O=S.V (2 mfma)
//       q=0 -> tRet bf16 (B,S,256); q=1..9 -> pat bf16 [b][h][9][4096][32]
//  4) k_fold: pat -> botRet bf16 (B,Sb,256) (gather <=4 windows, no atomics)
//  5) k_fuse: fuse-top + fuse-bot merged: C[m=o][n=pixrow] = Wf . ret^T -> fp32 d_out

typedef __attribute__((ext_vector_type(8))) short  bh8;
typedef __attribute__((ext_vector_type(4))) short  bh4;
typedef __attribute__((ext_vector_type(4))) float  f32x4;
typedef unsigned short u16;

static __device__ __forceinline__ u16 f2b(float x) {
    __hip_bfloat16 h = __float2bfloat16(x);
    return __builtin_bit_cast(u16, h);
}
static __device__ __forceinline__ float b2f(u16 u) {
    unsigned v = ((unsigned)u) << 16;
    return __builtin_bit_cast(float, v);
}

// async global->LDS, 16B per lane. Dest must be linear in lane (wave-uniform base + lane*16).
static __device__ __forceinline__ void gload16(const u16* g, u16* l) {
    __builtin_amdgcn_global_load_lds(
        (const __attribute__((address_space(1))) unsigned int*)g,
        (__attribute__((address_space(3))) unsigned int*)l, 16, 0, 0);
}

// ---------------- weight convert: 8 x 256x256 fp32 -> bf16 ----------------
__global__ __launch_bounds__(256) void k_cvt_w(
    const float* w0, const float* w1, const float* w2, const float* w3,
    const float* w4, const float* w5, const float* w6, const float* w7,
    u16* __restrict__ Wb)
{
    const float* srcs[8] = {w0,w1,w2,w3,w4,w5,w6,w7};
    const float* src = srcs[blockIdx.y];
    int i = (blockIdx.x * 256 + threadIdx.x) * 4;
    float4 v = *(const float4*)&src[i];
    u16 tmp[4] = { f2b(v.x), f2b(v.y), f2b(v.z), f2b(v.w) };
    *(uint2*)&Wb[(size_t)blockIdx.y * 65536 + i] = *(uint2*)tmp;
}

// ---------------- proj (top + bot merged), transpose fused into A-staging ----------------
// grid (3, 640): y<128 top (m-tile y), else bot (m-tile y-128). N=768=[K|Q|V].
// A[m=pix][k=c] from channel-major fp32 feat: lane=pix, 8 coalesced dword rows
// per chunk -> cvt -> ds_write_b128 at XOR-swizzled slot (write swz == read swz).
// B from Wb bf16 via gload16 with pre-swizzled source (round-3 verified).
// store: Yp[(n>>8)*arrsz + m*256 + (n&255)]  (pixel-major K/Q/V)
__global__ __launch_bounds__(256) void k_proj(
    const float* __restrict__ top_feat, const float* __restrict__ bot_feat,
    const u16* __restrict__ Wb,
    u16* __restrict__ tK, u16* __restrict__ bK, size_t TOPU, size_t BOTU)
{
    const int yb    = blockIdx.y;
    const bool istop = yb < 128;
    const float* feat = istop ? top_feat : bot_feat;
    const u16* Bw   = istop ? Wb : (Wb + 3 * 65536);
    u16* Yp         = istop ? tK : bK;
    const size_t arrsz = istop ? TOPU : BOTU;
    const int S     = istop ? 4096 : 16384;
    const int m0g   = (istop ? yb : (yb - 128)) * 64;      // global output row base
    const int b     = istop ? (m0g >> 12) : (m0g >> 14);
    const int pix0  = m0g & (S - 1);
    const float* Xb = feat + (size_t)b * 256 * S;
    const int n0 = blockIdx.x * 256;
    const int t  = threadIdx.x;
    const int w  = t >> 6, wl = t & 63, l16 = wl & 15, grp = wl >> 4;
    const int apix = t & 63;       // lane's pixel for A staging
    const int aq   = t >> 6;       // quarter -> chunks {2aq, 2aq+1}

    __shared__ __align__(16) u16 AT[2][64 * 64];
    __shared__ __align__(16) u16 BT[2][256 * 64];

    float rA[2][8];

#define PROJ_A_LOAD(kk) do {                                                  \
        _Pragma("unroll")                                                     \
        for (int cc = 0; cc < 2; ++cc)                                        \
            _Pragma("unroll")                                                 \
            for (int e = 0; e < 8; ++e)                                       \
                rA[cc][e] = Xb[(size_t)((kk) + (2*aq + cc)*8 + e) * S         \
                               + pix0 + apix];                                \
    } while (0)

#define PROJ_A_WRITE(bufi) do {                                               \
        _Pragma("unroll")                                                     \
        for (int cc = 0; cc < 2; ++cc) {                                      \
            int cg = 2*aq + cc, slot = cg ^ (apix & 7);                       \
            u16 tmp[8];                                                       \
            _Pragma("unroll")                                                 \
            for (int e = 0; e < 8; ++e) tmp[e] = f2b(rA[cc][e]);              \
            *(uint4*)&AT[bufi][apix * 64 + slot * 8] = *(uint4*)tmp;          \
        }                                                                     \
    } while (0)

#define PROJ_STAGE_B(bufi, kk) do {                                           \
        _Pragma("unroll")                                                     \
        for (int it = 0; it < 8; ++it) {                                      \
            int lin = it * 256 + t;                                           \
            int row = lin >> 3, c = lin & 7;                                  \
            int cs = c ^ (row & 7);                                           \
            gload16(&Bw[(size_t)(n0 + row) * 256 + (kk) + cs * 8],            \
                    &BT[bufi][lin * 8]);                                      \
        }                                                                     \
    } while (0)

    f32x4 acc[4][4];
    #pragma unroll
    for (int i = 0; i < 4; ++i)
        #pragma unroll
        for (int j = 0; j < 4; ++j) acc[i][j] = (f32x4){0.f, 0.f, 0.f, 0.f};

    PROJ_A_LOAD(0);
    PROJ_STAGE_B(0, 0);
    PROJ_A_WRITE(0);
    int cur = 0;
    for (int kt = 0; kt < 4; ++kt) {
        __syncthreads();   // drains B gloads + A ds_writes for buf[cur]
        if (kt < 3) {
            PROJ_A_LOAD((kt + 1) * 64);          // issue early (hides under MFMA)
            PROJ_STAGE_B(cur ^ 1, (kt + 1) * 64);
        }
        #pragma unroll
        for (int ks = 0; ks < 2; ++ks) {
            bh8 af[4], bf[4];
            #pragma unroll
            for (int mi = 0; mi < 4; ++mi) {
                int row = mi * 16 + l16;
                int pc = (ks * 4 + grp) ^ (row & 7);
                af[mi] = *(const bh8*)&AT[cur][row * 64 + pc * 8];
            }
            #pragma unroll
            for (int ni = 0; ni < 4; ++ni) {
                int row = w * 64 + ni * 16 + l16;
                int pc = (ks * 4 + grp) ^ (row & 7);
                bf[ni] = *(const bh8*)&BT[cur][row * 64 + pc * 8];
            }
            #pragma unroll
            for (int mi = 0; mi < 4; ++mi)
                #pragma unroll
                for (int ni = 0; ni < 4; ++ni)
                    acc[mi][ni] = __builtin_amdgcn_mfma_f32_16x16x32_bf16(
                        af[mi], bf[ni], acc[mi][ni], 0, 0, 0);
        }
        if (kt < 3) PROJ_A_WRITE(cur ^ 1);       // cvt+write late (loads landed)
        cur ^= 1;
    }
#undef PROJ_A_LOAD
#undef PROJ_A_WRITE
#undef PROJ_STAGE_B

    #pragma unroll
    for (int mi = 0; mi < 4; ++mi)
        #pragma unroll
        for (int ni = 0; ni < 4; ++ni)
            #pragma unroll
            for (int r = 0; r < 4; ++r) {
                int m = m0g + mi*16 + grp*4 + r;
                int n = n0 + w*64 + ni*16 + l16;
                Yp[(size_t)(n >> 8) * arrsz + (size_t)m * 256 + (n & 255)]
                    = f2b(acc[mi][ni][r]);
            }
}

// Shared GEMM staging/compute for k_fuse (round-3 verified): C[m][n]=sum_k A[m][k]*B[n][k].
#define GEMM_STAGE(bufi, kk) do {                                             \
        _Pragma("unroll")                                                     \
        for (int it = 0; it < 2; ++it) {                                      \
            int lin = it * 256 + t;                                           \
            int row = lin >> 3, c = lin & 7;                                  \
            int cs = c ^ (row & 7);                                           \
            gload16(&A[(size_t)(m0 + row) * 256 + (kk) + cs * 8],             \
                    &AT[bufi][lin * 8]);                                      \
        }                                                                     \
        _Pragma("unroll")                                                     \
        for (int it = 0; it < 8; ++it) {                                      \
            int lin = it * 256 + t;                                           \
            int row = lin >> 3, c = lin & 7;                                  \
            int cs = c ^ (row & 7);                                           \
            gload16(&B[(size_t)(n0 + row) * 256 + (kk) + cs * 8],             \
                    &BT[bufi][lin * 8]);                                      \
        }                                                                     \
    } while (0)

#define GEMM_MAIN()                                                           \
    GEMM_STAGE(0, 0);                                                         \
    int cur = 0;                                                              \
    for (int kt = 0; kt < 4; ++kt) {                                          \
        __syncthreads();                                                      \
        if (kt < 3) GEMM_STAGE(cur ^ 1, (kt + 1) * 64);                       \
        _Pragma("unroll")                                                     \
        for (int ks = 0; ks < 2; ++ks) {                                      \
            bh8 af[4], bf[4];                                                 \
            _Pragma("unroll")                                                 \
            for (int mi = 0; mi < 4; ++mi) {                                  \
                int row = mi * 16 + l16;                                      \
                int pc = (ks * 4 + grp) ^ (row & 7);                          \
                af[mi] = *(const bh8*)&AT[cur][row * 64 + pc * 8];            \
            }                                                                 \
            _Pragma("unroll")                                                 \
            for (int ni = 0; ni < 4; ++ni) {                                  \
                int row = w * 64 + ni * 16 + l16;                             \
                int pc = (ks * 4 + grp) ^ (row & 7);                          \
                bf[ni] = *(const bh8*)&BT[cur][row * 64 + pc * 8];            \
            }                                                                 \
            _Pragma("unroll")                                                 \
            for (int mi = 0; mi < 4; ++mi)                                    \
                _Pragma("unroll")                                             \
                for (int ni = 0; ni < 4; ++ni)                                \
                    acc[mi][ni] = __builtin_amdgcn_mfma_f32_16x16x32_bf16(    \
                        af[mi], bf[ni], acc[mi][ni], 0, 0, 0);                \
        }                                                                     \
        cur ^= 1;                                                             \
    }

// ---------------- fuse (top + bot merged): C[m=o][n=pixrow] -> fp32 ----------------
// blocks [0,128): top (lgS=12, n-tiles 32, m-tiles 4); [128,640): bot (lgS=14, 128x4)
__global__ __launch_bounds__(256) void k_fuse(
    const u16* __restrict__ Wb, const u16* __restrict__ tRet,
    const u16* __restrict__ botRet, float* __restrict__ top_out,
    float* __restrict__ bot_out)
{
    const int bid = blockIdx.x;
    const u16* A; const u16* B; float* Yf; int lgS, n0, m0;
    if (bid < 128) {
        A = Wb + 6 * 65536; B = tRet; Yf = top_out; lgS = 12;
        n0 = (bid & 31) * 256; m0 = (bid >> 5) * 64;
    } else {
        int i = bid - 128;
        A = Wb + 7 * 65536; B = botRet; Yf = bot_out; lgS = 14;
        n0 = (i & 127) * 256; m0 = (i >> 7) * 64;
    }
    const int t  = threadIdx.x;
    const int w  = t >> 6, wl = t & 63, l16 = wl & 15, grp = wl >> 4;

    __shared__ __align__(16) u16 AT[2][64 * 64];
    __shared__ __align__(16) u16 BT[2][256 * 64];

    f32x4 acc[4][4];
    #pragma unroll
    for (int i = 0; i < 4; ++i)
        #pragma unroll
        for (int j = 0; j < 4; ++j) acc[i][j] = (f32x4){0.f, 0.f, 0.f, 0.f};

    GEMM_MAIN();

    #pragma unroll
    for (int mi = 0; mi < 4; ++mi)
        #pragma unroll
        for (int ni = 0; ni < 4; ++ni)
            #pragma unroll
            for (int r = 0; r < 4; ++r) {
                int m = m0 + mi*16 + grp*4 + r;
                int n = n0 + w*64 + ni*16 + l16;
                int bb = n >> lgS, s = n & ((1 << lgS) - 1);
                Yf[(((size_t)bb * 256 + m) << lgS) + s] = acc[mi][ni][r];
            }
}

// ---------------- attention: one wave per (pixel, head-pair) ----------------
__global__ __launch_bounds__(256) void k_attn(
    const u16* __restrict__ tK, const u16* __restrict__ tQ, const u16* __restrict__ tV,
    const u16* __restrict__ bK, const u16* __restrict__ bQ, const u16* __restrict__ bV,
    u16* __restrict__ tRet, u16* __restrict__ pat)
{
    const int pix = blockIdx.x;     // 0..4095
    const int b   = blockIdx.y;
    const int w   = threadIdx.x >> 6;
    const int wl  = threadIdx.x & 63;
    const int l16 = wl & 15, grp = wl >> 4;
    const int y = pix >> 6, x = pix & 63;

    __shared__ u16 Ssm[4][16][24];        // [wave][q][kpos], stride 48B
    __shared__ __align__(16) u16 Vsm[4][2][16][16]; // [wave][v-half][kpos][v16]

    // position p = l16: p=0 top pixel, p=1..9 bot neighbor, p>=10 pad
    const int p = l16;
    bool pvalid = false; int bpix = 0; const bool istop = (p == 0);
    if (p == 0) pvalid = true;
    else if (p < 10) {
        int pm = p - 1; int i = (pm * 11) >> 5; int j = pm - 3 * i;
        int by = 2 * y + i - 1, bx = 2 * x + j - 1;
        pvalid = ((unsigned)by < 128u) && ((unsigned)bx < 128u);
        bpix = by * 128 + bx;
    }
    const size_t topRow = ((size_t)b * 4096  + pix)  * 256;
    const size_t botRow = ((size_t)b * 16384 + bpix) * 256;
    const float scale = 0.17677669529663687f; // 1/sqrt(32)

    #pragma unroll
    for (int hi = 0; hi < 2; ++hi) {
        const int h = w + hi * 4;
        const size_t off = (istop ? topRow : botRow) + h * 32 + grp * 8;
        bh8 aQ = {}, aK = {}, vV = {};
        if (pvalid) {
            if (istop) {
                aQ = *(const bh8*)(tQ + off);
                aK = *(const bh8*)(tK + off);
                vV = *(const bh8*)(tV + off);
            } else {
                aQ = *(const bh8*)(bQ + off);
                aK = *(const bh8*)(bK + off);
                vV = *(const bh8*)(bV + off);
            }
        }
        // stage V rows (zeros for invalid rows): half = grp>>1, chunk (grp&1)*8
        *(bh8*)&Vsm[w][grp >> 1][p][(grp & 1) * 8] = vV;

        // S = Q.K^T   (A rows = query pos, B cols = key pos, k = d contiguous)
        f32x4 z = {0.f, 0.f, 0.f, 0.f};
        f32x4 sC = __builtin_amdgcn_mfma_f32_16x16x32_bf16(aQ, aK, z, 0, 0, 0);
        #pragma unroll
        for (int r = 0; r < 4; ++r)
            Ssm[w][grp * 4 + r][l16] = f2b(sC[r] * scale);

        // A_S: row q=l16, k-slots (grp,i<4) = kpos 4*grp+i ; slots i>=4 zero
        bh8 aS = {};
        *(bh4*)&aS = *(const bh4*)&Ssm[w][l16][grp * 4];

        // B_V: slot (grp,i<4) = V[kpos=4*grp+i][v], consistent with A_S labeling
        bh8 bv0 = {}, bv1 = {};
        #pragma unroll
        for (int j = 0; j < 4; ++j) {
            bv0[j] = (short)Vsm[w][0][grp * 4 + j][l16];
            bv1[j] = (short)Vsm[w][1][grp * 4 + j][l16];
        }
        f32x4 oc0 = __builtin_amdgcn_mfma_f32_16x16x32_bf16(aS, bv0, z, 0, 0, 0);
        f32x4 oc1 = __builtin_amdgcn_mfma_f32_16x16x32_bf16(aS, bv1, z, 0, 0, 0);

        // outputs: row q = grp*4+r, col v = l16 (+16 for oc1)
        if (grp == 0) {
            size_t o = topRow + (size_t)h * 32;
            tRet[o + l16]      = f2b(oc0[0]);
            tRet[o + 16 + l16] = f2b(oc1[0]);
        }
        #pragma unroll
        for (int r = 0; r < 4; ++r) {
            int q = grp * 4 + r;
            if (q >= 1 && q <= 9) {
                size_t base = ((((size_t)b * 8 + h) * 9 + (q - 1)) * 4096 + pix) * 32;
                pat[base + l16]      = f2b(oc0[r]);
                pat[base + 16 + l16] = f2b(oc1[r]);
            }
        }
    }
}

// ---------------- fold: pat [b][h][9][4096][32] -> botRet (B,16384,256) bf16 ----------------
__global__ __launch_bounds__(256) void k_fold(
    const u16* __restrict__ pat, u16* __restrict__ botRet)
{
    int tid = blockIdx.x * 256 + threadIdx.x;       // 1,048,576 threads
    int vchunk = tid & 3;                           // 8 v's each
    int ri = tid >> 2;                              // (b*16384 + bpix)*8 + h
    int b = ri >> 17;
    int bpix = (ri >> 3) & 16383;
    int h = ri & 7;
    int by = bpix >> 7, bx = bpix & 127;
    int v0 = vchunk * 8;

    float acc[8];
    #pragma unroll
    for (int e = 0; e < 8; ++e) acc[e] = 0.f;

    for (int iy = 0; iy < 3; ++iy) {
        int ty = by + 1 - iy;
        if (ty & 1) continue;
        int yy = ty >> 1;
        if ((unsigned)yy >= 64u) continue;
        for (int jx = 0; jx < 3; ++jx) {
            int tx = bx + 1 - jx;
            if (tx & 1) continue;
            int xx = tx >> 1;
            if ((unsigned)xx >= 64u) continue;
            int q = iy * 3 + jx;
            size_t addr = ((((size_t)b * 8 + h) * 9 + q) * 4096 + (yy * 64 + xx)) * 32 + v0;
            uint4 pv = *(const uint4*)&pat[addr];
            const u16* pp = (const u16*)&pv;
            #pragma unroll
            for (int e = 0; e < 8; ++e) acc[e] += b2f(pp[e]);
        }
    }
    u16 tmp[8];
    #pragma unroll
    for (int e = 0; e < 8; ++e) tmp[e] = f2b(acc[e]);
    *(uint4*)&botRet[((size_t)b * 16384 + bpix) * 256 + h * 32 + v0] = *(uint4*)tmp;
}

extern "C" void kernel_launch(void* const* d_in, const int* in_sizes, int n_in,
                              void* d_out, int out_size, void* d_ws, size_t ws_size,
                              hipStream_t stream) {
    const float* top_feat = (const float*)d_in[0];
    const float* bot_feat = (const float*)d_in[1];

    float* out     = (float*)d_out;
    float* top_out = out;                            // (2,256,64,64)
    float* bot_out = out + (size_t)2 * 256 * 4096;   // (2,256,128,128)

    const size_t TOPU = (size_t)2 * 4096  * 256;   // ushort counts
    const size_t BOTU = (size_t)2 * 16384 * 256;
    char* p = (char*)d_ws;
    u16* Wb     = (u16*)p;  p += (size_t)8 * 65536 * 2;   // 1.0 MB
    u16* tK     = (u16*)p;  p += TOPU * 2;
    u16* tQ     = (u16*)p;  p += TOPU * 2;
    u16* tV     = (u16*)p;  p += TOPU * 2;                // 12.6 MB
    u16* bK     = (u16*)p;  p += BOTU * 2;
    u16* bQ     = (u16*)p;  p += BOTU * 2;
    u16* bV     = (u16*)p;  p += BOTU * 2;                // 50.3 MB
    u16* tRet   = (u16*)p;  p += TOPU * 2;                // 4.2 MB
    u16* pat    = (u16*)p;  p += (size_t)2*8*9*4096*32*2; // 37.7 MB
    u16* botRet = (u16*)p;  p += BOTU * 2;                // 16.8 MB  (~122.6 MB total)

    dim3 blk(256);

    // weights -> bf16 (order: tK,tQ,tV,bK,bQ,bV,tFuse,bFuse)
    k_cvt_w<<<dim3(64, 8), blk, 0, stream>>>(
        (const float*)d_in[2], (const float*)d_in[3], (const float*)d_in[4],
        (const float*)d_in[5], (const float*)d_in[6], (const float*)d_in[7],
        (const float*)d_in[8], (const float*)d_in[9], Wb);

    // fused QKV projections, top+bot merged, transpose fused into A-staging
    k_proj<<<dim3(3, 640), blk, 0, stream>>>(top_feat, bot_feat, Wb,
                                             tK, bK, TOPU, BOTU);

    // attention
    k_attn<<<dim3(4096, 2), blk, 0, stream>>>(tK, tQ, tV, bK, bQ, bV, tRet, pat);

    // fold bot windows
    k_fold<<<dim3(4096), blk, 0, stream>>>(pat, botRet);

    // fuse GEMMs, top+bot merged -> fp32 channel-major outputs
    k_fuse<<<dim3(640), blk, 0, stream>>>(Wb, tRet, botRet, top_out, bot_out);
}